// Round 9
// baseline (439.045 us; speedup 1.0000x reference)
//
#include <hip/hip_runtime.h>

// Two-layer bidirectional LSTM, S=512, B=8192, I=3, H=5.
// R25: layer1 pair-per-row rewrite. Cross-round data: per-wave step wall
// pinned ~905cy in all bperm layouts (stall ~545 from the LDS broadcast
// round-trip + few-rows-per-wave overhead); R23's DPP-only chain had
// ~300 stall but 2x issue (4x redundant cell). New layout: lane pair
// (2k,2k+1) owns one (b,dir) row; par=0 computes gates (i,f) x 5 units,
// par=1 computes (g,o); ONE quad_perm DPP swap [1,0,3,2] exchanges the
// 10 gate values inside the pair (VALU pipe, no LDS); cell computed
// redundantly in both lanes (2x, ~10 extra trans/row) -> h,c in-register
// everywhere; chain is pure VALU (~80cy), hidden under issue.
// 32 rows/wave (64/64 lanes), 512 single-wave blocks = 2/CU.
// MITM: TL=240 LDS stash (76.8KB -> exactly 2 blocks/CU) + 16-step
// compact spill (2.6MB), vmcnt(0) at boundary, 640B full-sector out
// runs, fp16 stash, parity-uniform cell algebra (2 cndmask/unit).
// Layer0 unchanged from R24.

constexpr int S_ = 512;
constexpr int B_ = 8192;
constexpr int NROW = 16384;    // 2 dirs * 8192

constexpr int GD1 = 512;           // layer1 grid: 16 b x 2 dirs per wave
constexpr int TL1 = 240;           // layer1 phi1 steps resident in LDS

constexpr float L2E  = 1.4426950408889634f;   // log2(e)
constexpr float T2E  = 2.8853900817779268f;   // 2*log2(e)
constexpr float IT2E = 0.34657359027997264f;  // 1/(2*log2(e))

typedef _Float16 v2h __attribute__((ext_vector_type(2)));

__device__ __forceinline__ float dot2h(v2h a, v2h b, float c) {
#if __has_builtin(__builtin_amdgcn_fdot2)
    return __builtin_amdgcn_fdot2(a, b, c, false);
#else
    return fmaf((float)a[0], (float)b[0], fmaf((float)a[1], (float)b[1], c));
#endif
}

__device__ __forceinline__ float rcp_(float x) { return __builtin_amdgcn_rcpf(x); }

__device__ __forceinline__ float exp2_(float x) {
#if __has_builtin(__builtin_amdgcn_exp2f)
    return __builtin_amdgcn_exp2f(x);
#else
    return exp2f(x);
#endif
}

__device__ __forceinline__ void sbar() { __builtin_amdgcn_sched_barrier(0); }

// full-wave backward permute: dst = src[lane bidx/4] (layer0 only)
__device__ __forceinline__ float bperm(int bidx, float v) {
    return __int_as_float(__builtin_amdgcn_ds_bpermute(bidx, __float_as_int(v)));
}

// quad_perm [1,0,3,2]: swap adjacent lane pairs within each quad (VALU DPP)
__device__ __forceinline__ float dsw(float v) {
    return __int_as_float(__builtin_amdgcn_update_dpp(
        0, __float_as_int(v), 0xB1, 0xF, 0xF, false));
}

__device__ __forceinline__ unsigned pkh(float a, float b) {
    auto t = __builtin_amdgcn_cvt_pkrtz(a, b);   // __fp16 ext_vector(2)
    unsigned q; __builtin_memcpy(&q, &t, 4); return q;
}

__device__ __forceinline__ unsigned short f2h(float x) {
    _Float16 h = (_Float16)x;                    // RTE
    unsigned short s; __builtin_memcpy(&s, &h, 2); return s;
}

__device__ __forceinline__ float h2f(unsigned short s) {
    _Float16 h; __builtin_memcpy(&h, &s, 2); return (float)h;
}

// ------- Layer 0: x [S][B][3] f32 -> ws planes [2][S][B] 12B fp16 rows -------
__global__ __launch_bounds__(64) __attribute__((amdgpu_waves_per_eu(1, 2)))
void lstm_layer0(
    const float* __restrict__ x,
    const float* __restrict__ wih_f, const float* __restrict__ whh_f,
    const float* __restrict__ bih_f, const float* __restrict__ bhh_f,
    const float* __restrict__ wih_r, const float* __restrict__ whh_r,
    const float* __restrict__ bih_r, const float* __restrict__ bhh_r,
    unsigned short* __restrict__ ws,
    float* __restrict__ outbase)
{
    const int l64 = threadIdx.x & 63;
    int r = l64 / 5; r = (r > 11) ? 11 : r;     // row-in-wave 0..11
    const int u   = l64 - r * 5;                // 0..4 active (5..8 on idle lanes)
    const int uc  = (u < 5) ? u : 4;
    const int gid = blockIdx.x * 12 + r;
    const bool valid = gid < NROW;
    const int dir = (gid >> 13) & 1;
    const int b   = gid & 8191;
    const bool stw = valid && (u < 3);          // per-lane dword row-store
    const bool st  = valid && (u < 5);          // epilogue-store lanes

    int bidx[5];
#pragma unroll
    for (int k = 0; k < 5; k++) bidx[k] = (r * 5 + k) * 4;

    const float* __restrict__ wih = dir ? wih_r : wih_f;
    const float* __restrict__ whh = dir ? whh_r : whh_f;
    const float* __restrict__ bih = dir ? bih_r : bih_f;
    const float* __restrict__ bhh = dir ? bhh_r : bhh_f;

    // 4 gate rows for unit uc: i,f,g,o = rows uc, 5+uc, 10+uc, 15+uc
    const int rows[4] = {uc, 5 + uc, 10 + uc, 15 + uc};
    const float scl[4] = {-L2E, -L2E, T2E, -L2E};
    float WX[4][3], WH[4][5], BS[4];
#pragma unroll
    for (int gi = 0; gi < 4; gi++) {
        const int rr = rows[gi]; const float sc = scl[gi];
#pragma unroll
        for (int i = 0; i < 3; i++) WX[gi][i] = wih[rr * 3 + i] * sc;
#pragma unroll
        for (int k = 0; k < 5; k++) WH[gi][k] = whh[rr * 5 + k] * sc;
        BS[gi] = (bih[rr] + bhh[rr]) * sc;
    }

    float h[5] = {0.f, 0.f, 0.f, 0.f, 0.f};
    float cp = 0.f, hu_last = 0.f;              // cp = c * 2log2e

    const int t0 = dir ? (S_ - 1) : 0;
    const float* xp = x + ((size_t)t0 * B_ + b) * 3;
    unsigned short* wp = ws + (size_t)dir * ((size_t)S_ * B_ * 6)
                            + ((size_t)t0 * B_ + b) * 6;
    const ptrdiff_t xst = dir ? -(ptrdiff_t)3 * B_ : (ptrdiff_t)3 * B_;
    const ptrdiff_t wst = dir ? -(ptrdiff_t)6 * B_ : (ptrdiff_t)6 * B_;

    auto step = [&](const float (&xin)[3], unsigned short* wpp) {
        float a0 = BS[0], a1 = BS[1], a2 = BS[2], a3 = BS[3];
#pragma unroll
        for (int i = 0; i < 3; i++) {
            a0 = fmaf(WX[0][i], xin[i], a0);
            a1 = fmaf(WX[1][i], xin[i], a1);
            a2 = fmaf(WX[2][i], xin[i], a2);
            a3 = fmaf(WX[3][i], xin[i], a3);
        }
#pragma unroll
        for (int k = 0; k < 5; k++) {
            a0 = fmaf(WH[0][k], h[k], a0);
            a1 = fmaf(WH[1][k], h[k], a1);
            a2 = fmaf(WH[2][k], h[k], a2);
            a3 = fmaf(WH[3][k], h[k], a3);
        }
        const float ig = rcp_(1.0f + exp2_(a0));
        const float fg = rcp_(1.0f + exp2_(a1));
        const float g2 = fmaf(-2.0f * T2E, rcp_(1.0f + exp2_(a2)), T2E);
        const float og = rcp_(1.0f + exp2_(a3));
        cp = fmaf(fg, cp, ig * g2);
        const float th = fmaf(-2.0f, rcp_(1.0f + exp2_(cp)), 1.0f);
        const float hu = og * th;
        hu_last = hu;
#pragma unroll
        for (int k = 0; k < 5; k++) h[k] = bperm(bidx[k], hu);
        const unsigned q0 = pkh(h[0], h[1]);
        const unsigned q1 = pkh(h[2], h[3]);
        const unsigned q2 = pkh(h[4], 0.0f);
        unsigned qs = q0;
        qs = (u == 1) ? q1 : qs;
        qs = (u == 2) ? q2 : qs;
        if (stw) ((unsigned*)wpp)[u] = qs;
    };

    auto ld = [&](float (&buf)[3]) {
        __builtin_memcpy(&buf[0], xp, 12);
        xp += xst;
        sbar();
    };

    float x0[3], x1[3], x2[3], x3[3], x4[3], x5[3], x6[3], x7[3];
    ld(x0); ld(x1); ld(x2); ld(x3); ld(x4); ld(x5); ld(x6); ld(x7);

#pragma unroll 1
    for (int s = 0; s < S_ - 8; s += 8) {
        step(x0, wp); wp += wst; ld(x0);
        step(x1, wp); wp += wst; ld(x1);
        step(x2, wp); wp += wst; ld(x2);
        step(x3, wp); wp += wst; ld(x3);
        step(x4, wp); wp += wst; ld(x4);
        step(x5, wp); wp += wst; ld(x5);
        step(x6, wp); wp += wst; ld(x6);
        step(x7, wp); wp += wst; ld(x7);
    }
    step(x0, wp); wp += wst;
    step(x1, wp); wp += wst;
    step(x2, wp); wp += wst;
    step(x3, wp); wp += wst;
    step(x4, wp); wp += wst;
    step(x5, wp); wp += wst;
    step(x6, wp); wp += wst;
    step(x7, wp);

    const size_t OUTE = (size_t)S_ * B_ * 10;
    float* hn = outbase + OUTE + ((size_t)dir * B_ + b) * 5;
    float* cn = hn + (size_t)4 * B_ * 5;
    if (st) { hn[uc] = hu_last; cn[uc] = cp * IT2E; }
}

// ------- Layer 1: pair-per-row (par 0:(i,f), 1:(g,o)), DPP swap, MITM -------
__global__ __launch_bounds__(64) __attribute__((amdgpu_waves_per_eu(1)))
void lstm_layer1(
    const unsigned short* __restrict__ ws,
    const float* __restrict__ wih_f, const float* __restrict__ whh_f,
    const float* __restrict__ bih_f, const float* __restrict__ bhh_f,
    const float* __restrict__ wih_r, const float* __restrict__ whh_r,
    const float* __restrict__ bih_r, const float* __restrict__ bhh_r,
    float* __restrict__ outbase,
    unsigned short* __restrict__ gtemp)
{
    __shared__ unsigned       ltA[TL1 * 64];    // pkh pairs: 61440 B
    __shared__ unsigned short ltB[TL1 * 32];    // h4:        15360 B

    const int l64 = threadIdx.x & 63;
    const int bid = (int)blockIdx.x;
    const int bsw = (bid & 7) * 64 + (bid >> 3);    // 512 = 8*64, bijective
    const int par = l64 & 1;                    // 0 -> (i,f), 1 -> (g,o)
    const int k   = l64 >> 1;                   // pair/row 0..31
    const int dir = k >> 4;                     // rows 0-15 fwd, 16-31 bwd
    const int b   = bsw * 16 + (k & 15);        // 512*16 = 8192 exact
    const int pk  = k ^ 16;                     // partner row (other dir)

    const float* __restrict__ wih = dir ? wih_r : wih_f;
    const float* __restrict__ whh = dir ? whh_r : whh_f;
    const float* __restrict__ bih = dir ? bih_r : bih_f;
    const float* __restrict__ bhh = dir ? bhh_r : bhh_f;

    // slot j<5: gate-group0 (par=0: i rows 0-4, par=1: g rows 10-14)
    // slot j>=5: gate-group1 (par=0: f rows 5-9, par=1: o rows 15-19)
    const int G0 = par ? 2 : 0, G1 = par ? 3 : 1;
    const float s0 = par ? T2E : -L2E;          // group0 prescale
    const float GM0 = par ? (-2.0f * T2E) : 1.0f;
    const float GB0 = par ? T2E : 0.0f;

    v2h  WX[10][6];
    float WH[10][5], BS[10];
#pragma unroll
    for (int u = 0; u < 5; u++) {
        const int rr0 = G0 * 5 + u, rr1 = G1 * 5 + u;
#pragma unroll
        for (int q = 0; q < 6; q++) {
            const int i0 = (q < 3) ? 2 * q : 2 * q - 1;   // 0,2,4,5,7,9
            const bool pad = (q == 2) || (q == 5);
            const float a0 = wih[rr0 * 10 + i0] * s0;
            const float a1 = pad ? 0.f : wih[rr0 * 10 + i0 + 1] * s0;
            WX[u][q] = (v2h){(_Float16)a0, (_Float16)a1};
            const float b0 = wih[rr1 * 10 + i0] * (-L2E);
            const float b1 = pad ? 0.f : wih[rr1 * 10 + i0 + 1] * (-L2E);
            WX[5 + u][q] = (v2h){(_Float16)b0, (_Float16)b1};
        }
#pragma unroll
        for (int kk = 0; kk < 5; kk++) {
            WH[u][kk]     = whh[rr0 * 5 + kk] * s0;
            WH[5 + u][kk] = whh[rr1 * 5 + kk] * (-L2E);
        }
        BS[u]     = (bih[rr0] + bhh[rr0]) * s0;
        BS[5 + u] = (bih[rr1] + bhh[rr1]) * (-L2E);
    }

    float h[5]  = {0.f, 0.f, 0.f, 0.f, 0.f};
    float cp[5] = {0.f, 0.f, 0.f, 0.f, 0.f};

    const int t0 = dir ? (S_ - 1) : 0;
    const unsigned short* rpf = ws + ((size_t)t0 * B_ + b) * 6;
    const unsigned short* rpb = rpf + (size_t)S_ * B_ * 6;
    const ptrdiff_t rst = dir ? -(ptrdiff_t)6 * B_ : (ptrdiff_t)6 * B_;
    // out: par=0 stores own half (col dir*5), par=1 stores partner half.
    float* op = outbase + ((size_t)(dir ? 255 : 256) * B_ + b) * 10
                        + (par ? (5 - dir * 5) : dir * 5);
    const ptrdiff_t ost = dir ? -(ptrdiff_t)10 * B_ : (ptrdiff_t)10 * B_;
    // spill: [block][tp 0..15][64 dwords pkh | 32 shorts h4] = 320B/tp
    unsigned short* gsp = gtemp + (size_t)bid * (16 * 160);

    auto ld = [&](v2h (&buf)[6]) {
        __builtin_memcpy(&buf[0], rpf, 12);
        __builtin_memcpy(&buf[3], rpb, 12);
        rpf += rst; rpb += rst;
        sbar();
    };

    float A[10];
    auto dots = [&](const v2h (&xin)[6]) {
#pragma unroll
        for (int j = 0; j < 10; j++) {
            float t = BS[j];
#pragma unroll
            for (int q = 0; q < 6; q++) t = dot2h(xin[q], WX[j][q], t);
            A[j] = t;
        }
    };
    // WH + nonlin + pair DPP swap + redundant cell (parity-uniform algebra)
    auto finish = [&]() {
#pragma unroll
        for (int j = 0; j < 10; j++) {
#pragma unroll
            for (int kk = 0; kk < 5; kk++) A[j] = fmaf(WH[j][kk], h[kk], A[j]);
        }
        float v0[5], v1[5], z0[5], z1[5];
#pragma unroll
        for (int u = 0; u < 5; u++) {
            v0[u] = fmaf(GM0, rcp_(1.0f + exp2_(A[u])), GB0);
            v1[u] = rcp_(1.0f + exp2_(A[5 + u]));
        }
#pragma unroll
        for (int u = 0; u < 5; u++) { z0[u] = dsw(v0[u]); z1[u] = dsw(v1[u]); }
        // par=0: i=v0, f=v1, g=z0, o=z1. par=1: g=v0, o=v1, i=z0, f=z1.
        // cp = F*cp + v0*z0 (i*g both ways); F = par? z1 : v1; O = par? v1 : z1.
#pragma unroll
        for (int u = 0; u < 5; u++) {
            const float F = par ? z1[u] : v1[u];
            const float O = par ? v1[u] : z1[u];
            cp[u] = fmaf(F, cp[u], v0[u] * z0[u]);
            const float th = fmaf(-2.0f, rcp_(1.0f + exp2_(cp[u])), 1.0f);
            h[u] = O * th;
        }
    };

    auto outst = [&](float p0, float p1, float p2, float p3, float p4) {
        float buf[5];
        buf[0] = par ? p0 : h[0];
        buf[1] = par ? p1 : h[1];
        buf[2] = par ? p2 : h[2];
        buf[3] = par ? p3 : h[3];
        buf[4] = par ? p4 : h[4];
        __builtin_memcpy(op, buf, 20);          // dwordx4 + dword
        op += ost;
    };

    // phase steps
    auto s1L = [&](v2h (&xb)[6], int t) {
        dots(xb); ld(xb); finish();
        const unsigned d = par ? pkh(h[2], h[3]) : pkh(h[0], h[1]);
        ltA[t * 64 + l64] = d;                  // lane l writes dword l: no conflicts
        if (!par) ltB[t * 32 + k] = f2h(h[4]);
    };
    auto s1G = [&](v2h (&xb)[6], int tp) {
        dots(xb); ld(xb); finish();
        const unsigned d = par ? pkh(h[2], h[3]) : pkh(h[0], h[1]);
        __builtin_memcpy(gsp + (size_t)tp * 160 + l64 * 2, &d, 4);
        if (!par) gsp[(size_t)tp * 160 + 128 + k] = f2h(h[4]);
    };
    auto s2G = [&](v2h (&xb)[6], int tp) {
        unsigned two[2];
        __builtin_memcpy(two, gsp + (size_t)tp * 160 + pk * 4, 8);
        const unsigned short s4 = gsp[(size_t)tp * 160 + 128 + pk];
        dots(xb); ld(xb); finish();
        v2h t01, t23;
        __builtin_memcpy(&t01, &two[0], 4); __builtin_memcpy(&t23, &two[1], 4);
        outst((float)t01[0], (float)t01[1], (float)t23[0], (float)t23[1], h2f(s4));
    };
    auto s2L = [&](v2h (&xb)[6], int tau) {
        const unsigned d01 = ltA[tau * 64 + 2 * pk];       // lane l -> dword l^32
        const unsigned d23 = ltA[tau * 64 + 2 * pk + 1];
        const unsigned short s4 = ltB[tau * 32 + pk];
        dots(xb); ld(xb); finish();
        v2h t01, t23;
        __builtin_memcpy(&t01, &d01, 4); __builtin_memcpy(&t23, &d23, 4);
        outst((float)t01[0], (float)t01[1], (float)t23[0], (float)t23[1], h2f(s4));
    };
    auto s2Ln = [&](v2h (&xb)[6], int tau) {    // tail: no x load
        const unsigned d01 = ltA[tau * 64 + 2 * pk];
        const unsigned d23 = ltA[tau * 64 + 2 * pk + 1];
        const unsigned short s4 = ltB[tau * 32 + pk];
        dots(xb); finish();
        v2h t01, t23;
        __builtin_memcpy(&t01, &d01, 4); __builtin_memcpy(&t23, &d23, 4);
        outst((float)t01[0], (float)t01[1], (float)t23[0], (float)t23[1], h2f(s4));
    };

    v2h x0[6], x1[6], x2[6], x3[6];
    ld(x0); ld(x1); ld(x2); ld(x3);             // t = 0..3

    // phi1a: t = 0..239 (LDS stash rows 0..239)
#pragma unroll 1
    for (int t = 0; t < TL1; t += 4) {
        s1L(x0, t + 0); s1L(x1, t + 1); s1L(x2, t + 2); s1L(x3, t + 3);
    }
    // phi1b: t = 240..255 (spill rows 0..15)
#pragma unroll 1
    for (int t = TL1; t < 256; t += 4) {
        s1G(x0, t - 240); s1G(x1, t - 239); s1G(x2, t - 238); s1G(x3, t - 237);
    }
    // drain: spill row 15 (written t=255) is read at t=256 by this wave.
    asm volatile("s_waitcnt vmcnt(0)" ::: "memory");
    // phi2a: t = 256..271, partner from spill row 271-t (15..0)
#pragma unroll 1
    for (int t = 256; t < 272; t += 4) {
        s2G(x0, 271 - t); s2G(x1, 270 - t); s2G(x2, 269 - t); s2G(x3, 268 - t);
    }
    // phi2b: t = 272..507, partner from LDS row 511-t (239..4)
#pragma unroll 1
    for (int t = 272; t < 508; t += 4) {
        s2L(x0, 511 - t); s2L(x1, 510 - t); s2L(x2, 509 - t); s2L(x3, 508 - t);
    }
    // tail: t = 508..511 (LDS rows 3..0), no more x loads
    s2Ln(x0, 3); s2Ln(x1, 2); s2Ln(x2, 1); s2Ln(x3, 0);

    // epilogue: par=0 -> h_n (slot 2+dir), par=1 -> c_n; both lanes hold all
    const size_t OUTE = (size_t)S_ * B_ * 10;
    float* hn = outbase + OUTE + ((size_t)(2 + dir) * B_ + b) * 5;
    float* cn = hn + (size_t)4 * B_ * 5;
    float* ep = par ? cn : hn;
    float eb[5];
#pragma unroll
    for (int u = 0; u < 5; u++) eb[u] = par ? cp[u] * IT2E : h[u];
    __builtin_memcpy(ep, eb, 20);
}

extern "C" void kernel_launch(void* const* d_in, const int* in_sizes, int n_in,
                              void* d_out, int out_size, void* d_ws, size_t ws_size,
                              hipStream_t stream) {
    const float* x       = (const float*)d_in[0];
    const float* wih_l0  = (const float*)d_in[1];
    const float* whh_l0  = (const float*)d_in[2];
    const float* bih_l0  = (const float*)d_in[3];
    const float* bhh_l0  = (const float*)d_in[4];
    const float* wih_l0r = (const float*)d_in[5];
    const float* whh_l0r = (const float*)d_in[6];
    const float* bih_l0r = (const float*)d_in[7];
    const float* bhh_l0r = (const float*)d_in[8];
    const float* wih_l1  = (const float*)d_in[9];
    const float* whh_l1  = (const float*)d_in[10];
    const float* bih_l1  = (const float*)d_in[11];
    const float* bhh_l1  = (const float*)d_in[12];
    const float* wih_l1r = (const float*)d_in[13];
    const float* whh_l1r = (const float*)d_in[14];
    const float* bih_l1r = (const float*)d_in[15];
    const float* bhh_l1r = (const float*)d_in[16];

    float* out = (float*)d_out;
    unsigned short* ws = (unsigned short*)d_ws;   // 2 planes * S*B*12B = 100.7 MB
    // layer1 spill: 512 blocks * 16 steps * 320B = 2.6 MB after the planes
    unsigned short* gtemp = ws + (size_t)2 * S_ * B_ * 6;

    // layer0: 16384 (dir,row) sequences, 12 per wave -> 1366 single-wave blocks
    dim3 grid0(1366), block(64);
    lstm_layer0<<<grid0, block, 0, stream>>>(x,
        wih_l0, whh_l0, bih_l0, bhh_l0,
        wih_l0r, whh_l0r, bih_l0r, bhh_l0r,
        ws, out);
    // layer1: 16 b x 2 dirs per wave (pair-per-row) -> 512 blocks = 2/CU
    dim3 grid1(GD1);
    lstm_layer1<<<grid1, block, 0, stream>>>(ws,
        wih_l1, whh_l1, bih_l1, bhh_l1,
        wih_l1r, whh_l1r, bih_l1r, bhh_l1r,
        out, gtemp);
}

// Round 10
// 319.471 us; speedup vs baseline: 1.3743x; 1.3743x over previous
//
#include <hip/hip_runtime.h>

// Two-layer bidirectional LSTM, S=512, B=8192, I=3, H=5.
// R26: 4-step-blocked ws layout (targets the measured l0<->l1 wall delta:
// layer1's 2x vmem instruction machinery). ws row = 48B block packing 4
// steps as [3 dword-groups][4 slots], 16B-aligned:
//  - layer0 accumulates 4 steps in acc[4] and stores ONE dwordx4 per
//    lane (u<3) every 4 steps (was 1 dword/step).
//  - layer1 loads 3 dwordx4 per plane per 4 steps (was 6 dwords/step);
//    slot select via compile-time-indexed cndmask: plane0 slot =
//    dir?3-p:p, plane1 slot = dir?p:3-p (slots written position-order
//    per plane, so l0 needs no dir-dependent indexing at all).
// Everything else identical to R24 (best, 309.9us): 12 rows/wave 5-lane
// groups, bperm h-bcast, MITM TL=208 LDS stash + 48-step spill ring,
// full-sector out runs, l1 XCD swizzle, l0 unswizzled, depth-8 x
// prefetch in l0, waves_per_eu(1,2).

constexpr int S_ = 512;
constexpr int B_ = 8192;
constexpr int NROW = 16384;    // 2 dirs * 8192

constexpr int GD1  = 1366;         // layer1 grid = ceil(8192/6)
constexpr int TL   = 208;          // phi1 steps resident in LDS
constexpr int GSTR = GD1 * 64;     // spill stride per step (shorts)

constexpr float L2E  = 1.4426950408889634f;   // log2(e)
constexpr float T2E  = 2.8853900817779268f;   // 2*log2(e)
constexpr float IT2E = 0.34657359027997264f;  // 1/(2*log2(e))

typedef _Float16 v2h __attribute__((ext_vector_type(2)));
typedef unsigned u32;

__device__ __forceinline__ float dot2h(v2h a, v2h b, float c) {
#if __has_builtin(__builtin_amdgcn_fdot2)
    return __builtin_amdgcn_fdot2(a, b, c, false);
#else
    return fmaf((float)a[0], (float)b[0], fmaf((float)a[1], (float)b[1], c));
#endif
}

__device__ __forceinline__ float rcp_(float x) { return __builtin_amdgcn_rcpf(x); }

__device__ __forceinline__ float exp2_(float x) {
#if __has_builtin(__builtin_amdgcn_exp2f)
    return __builtin_amdgcn_exp2f(x);
#else
    return exp2f(x);
#endif
}

__device__ __forceinline__ void sbar() { __builtin_amdgcn_sched_barrier(0); }

// full-wave backward permute: dst = src[lane bidx/4]
__device__ __forceinline__ float bperm(int bidx, float v) {
    return __int_as_float(__builtin_amdgcn_ds_bpermute(bidx, __float_as_int(v)));
}

__device__ __forceinline__ unsigned pkh(float a, float b) {
    auto t = __builtin_amdgcn_cvt_pkrtz(a, b);   // __fp16 ext_vector(2)
    unsigned q; __builtin_memcpy(&q, &t, 4); return q;
}

__device__ __forceinline__ unsigned short f2h(float x) {
    _Float16 h = (_Float16)x;                    // RTE
    unsigned short s; __builtin_memcpy(&s, &h, 2); return s;
}

__device__ __forceinline__ float h2f(unsigned short s) {
    _Float16 h; __builtin_memcpy(&h, &s, 2); return (float)h;
}

// bijective chunked XCD swizzle for a 1366-block grid (q=170, rem=6)
__device__ __forceinline__ int xswz1366(int bid) {
    const int xcd = bid & 7, loc = bid >> 3;
    const int base = (xcd < 6) ? xcd * 171 : 1026 + (xcd - 6) * 170;
    return base + loc;
}

// ws geometry: plane = 128 groups * B * 12 dwords; row block = 12 dwords.
constexpr int GRP = 128;                 // S/4
constexpr ptrdiff_t PLANE_DW = (ptrdiff_t)GRP * B_ * 12;

// ------- Layer 0: x [S][B][3] f32 -> ws 4-step blocks -------
__global__ __launch_bounds__(64) __attribute__((amdgpu_waves_per_eu(1, 2)))
void lstm_layer0(
    const float* __restrict__ x,
    const float* __restrict__ wih_f, const float* __restrict__ whh_f,
    const float* __restrict__ bih_f, const float* __restrict__ bhh_f,
    const float* __restrict__ wih_r, const float* __restrict__ whh_r,
    const float* __restrict__ bih_r, const float* __restrict__ bhh_r,
    unsigned short* __restrict__ ws,
    float* __restrict__ outbase)
{
    const int l64 = threadIdx.x & 63;
    int r = l64 / 5; r = (r > 11) ? 11 : r;     // row-in-wave 0..11
    const int u   = l64 - r * 5;                // 0..4 active (5..8 on idle lanes)
    const int uc  = (u < 5) ? u : 4;
    const int gid = blockIdx.x * 12 + r;        // no swizzle (R22 A/B: hurts)
    const bool valid = gid < NROW;
    const int dir = (gid >> 13) & 1;
    const int b   = gid & 8191;
    const bool stw = valid && (u < 3);          // dwordx4 row-store lanes
    const bool st  = valid && (u < 5);          // epilogue-store lanes

    int bidx[5];
#pragma unroll
    for (int k = 0; k < 5; k++) bidx[k] = (r * 5 + k) * 4;

    const float* __restrict__ wih = dir ? wih_r : wih_f;
    const float* __restrict__ whh = dir ? whh_r : whh_f;
    const float* __restrict__ bih = dir ? bih_r : bih_f;
    const float* __restrict__ bhh = dir ? bhh_r : bhh_f;

    // 4 gate rows for unit uc: i,f,g,o = rows uc, 5+uc, 10+uc, 15+uc
    const int rows[4] = {uc, 5 + uc, 10 + uc, 15 + uc};
    const float scl[4] = {-L2E, -L2E, T2E, -L2E};
    float WX[4][3], WH[4][5], BS[4];
#pragma unroll
    for (int gi = 0; gi < 4; gi++) {
        const int rr = rows[gi]; const float sc = scl[gi];
#pragma unroll
        for (int i = 0; i < 3; i++) WX[gi][i] = wih[rr * 3 + i] * sc;
#pragma unroll
        for (int k = 0; k < 5; k++) WH[gi][k] = whh[rr * 5 + k] * sc;
        BS[gi] = (bih[rr] + bhh[rr]) * sc;
    }

    float h[5] = {0.f, 0.f, 0.f, 0.f, 0.f};
    float cp = 0.f, hu_last = 0.f;              // cp = c * 2log2e

    const int t0 = dir ? (S_ - 1) : 0;
    const float* xp = x + ((size_t)t0 * B_ + b) * 3;
    const ptrdiff_t xst = dir ? -(ptrdiff_t)3 * B_ : (ptrdiff_t)3 * B_;
    // ws write pointer: plane dir, group g0, row b, lane dword-group u
    u32* wp = (u32*)ws + (size_t)dir * PLANE_DW
                       + ((size_t)(dir ? GRP - 1 : 0) * B_ + b) * 12 + u * 4;
    const ptrdiff_t wst4 = dir ? -(ptrdiff_t)B_ * 12 : (ptrdiff_t)B_ * 12;

    u32 acc[4];

    auto step = [&](const float (&xin)[3], int slot) {
        float a0 = BS[0], a1 = BS[1], a2 = BS[2], a3 = BS[3];
#pragma unroll
        for (int i = 0; i < 3; i++) {
            a0 = fmaf(WX[0][i], xin[i], a0);
            a1 = fmaf(WX[1][i], xin[i], a1);
            a2 = fmaf(WX[2][i], xin[i], a2);
            a3 = fmaf(WX[3][i], xin[i], a3);
        }
#pragma unroll
        for (int k = 0; k < 5; k++) {
            a0 = fmaf(WH[0][k], h[k], a0);
            a1 = fmaf(WH[1][k], h[k], a1);
            a2 = fmaf(WH[2][k], h[k], a2);
            a3 = fmaf(WH[3][k], h[k], a3);
        }
        const float ig = rcp_(1.0f + exp2_(a0));
        const float fg = rcp_(1.0f + exp2_(a1));
        const float g2 = fmaf(-2.0f * T2E, rcp_(1.0f + exp2_(a2)), T2E);
        const float og = rcp_(1.0f + exp2_(a3));
        cp = fmaf(fg, cp, ig * g2);
        const float th = fmaf(-2.0f, rcp_(1.0f + exp2_(cp)), 1.0f);
        const float hu = og * th;
        hu_last = hu;
#pragma unroll
        for (int k = 0; k < 5; k++) h[k] = bperm(bidx[k], hu);
        // lane u (<3) keeps dword u of the row for this step-slot
        const unsigned q0 = pkh(h[0], h[1]);
        const unsigned q1 = pkh(h[2], h[3]);
        const unsigned q2 = pkh(h[4], 0.0f);
        unsigned qs = q0;
        qs = (u == 1) ? q1 : qs;
        qs = (u == 2) ? q2 : qs;
        acc[slot] = qs;                          // slot is compile-time
    };

    auto flush = [&]() {
        if (stw) __builtin_memcpy(__builtin_assume_aligned(wp, 16), acc, 16);
        wp += wst4;
    };

    auto ld = [&](float (&buf)[3]) {
        __builtin_memcpy(&buf[0], xp, 12);
        xp += xst;
        sbar();
    };

    float x0[3], x1[3], x2[3], x3[3], x4[3], x5[3], x6[3], x7[3];
    ld(x0); ld(x1); ld(x2); ld(x3); ld(x4); ld(x5); ld(x6); ld(x7);

#pragma unroll 1
    for (int s = 0; s < S_ - 8; s += 8) {
        step(x0, 0); ld(x0);
        step(x1, 1); ld(x1);
        step(x2, 2); ld(x2);
        step(x3, 3); ld(x3); flush();
        step(x4, 0); ld(x4);
        step(x5, 1); ld(x5);
        step(x6, 2); ld(x6);
        step(x7, 3); ld(x7); flush();
    }
    step(x0, 0);
    step(x1, 1);
    step(x2, 2);
    step(x3, 3); flush();
    step(x4, 0);
    step(x5, 1);
    step(x6, 2);
    step(x7, 3); flush();

    const size_t OUTE = (size_t)S_ * B_ * 10;
    float* hn = outbase + OUTE + ((size_t)dir * B_ + b) * 5;
    float* cn = hn + (size_t)4 * B_ * 5;
    if (st) { hn[uc] = hu_last; cn[uc] = cp * IT2E; }
}

// ------- Layer 1: ws 4-step blocks -> out [S][B][10] f32, MITM -------
__global__ __launch_bounds__(64) __attribute__((amdgpu_waves_per_eu(1, 2)))
void lstm_layer1(
    const unsigned short* __restrict__ ws,
    const float* __restrict__ wih_f, const float* __restrict__ whh_f,
    const float* __restrict__ bih_f, const float* __restrict__ bhh_f,
    const float* __restrict__ wih_r, const float* __restrict__ whh_r,
    const float* __restrict__ bih_r, const float* __restrict__ bhh_r,
    float* __restrict__ outbase,
    unsigned short* __restrict__ gtemp)
{
    __shared__ unsigned short lt[TL * 60];      // 24960B -> 6 blocks/CU

    const int l64 = threadIdx.x & 63;
    const int bid = (int)blockIdx.x;
    const int bsw = xswz1366(bid);
    int r = l64 / 5; r = (r > 11) ? 11 : r;     // row-in-wave 0..11
    const int u   = l64 - r * 5;
    const int uc  = (u < 5) ? u : 4;
    const int rm  = (r < 6) ? r : r - 6;        // b-slot 0..5
    const int dir = (r >= 6) ? 1 : 0;           // rows 0-5 fwd, 6-11 bwd
    const int braw = bsw * 6 + rm;
    const bool valid = braw < B_;
    const int b   = valid ? braw : (B_ - 1);
    const bool st = valid && (u < 5);
    const bool lw = (l64 < 60);                 // stash lanes
    const int dir5 = dir * 5;
    const int pr  = dir ? (r - 6) : (r + 6);    // partner row in wave
    const int ps  = pr * 5 + uc;                // partner slot (row*5+unit)

    int bidx[5];
#pragma unroll
    for (int k = 0; k < 5; k++) bidx[k] = (r * 5 + k) * 4;

    const float* __restrict__ wih = dir ? wih_r : wih_f;
    const float* __restrict__ whh = dir ? whh_r : whh_f;
    const float* __restrict__ bih = dir ? bih_r : bih_f;
    const float* __restrict__ bhh = dir ? bhh_r : bhh_f;

    const int rows[4] = {uc, 5 + uc, 10 + uc, 15 + uc};
    const float scl[4] = {-L2E, -L2E, T2E, -L2E};
    // x-weights as fp16 pairs: fwd-plane pairs p=0..2 ((w0,w1)(w2,w3)(w4,0)),
    // bwd-plane pairs p=3..5 ((w5,w6)(w7,w8)(w9,0))
    v2h WX[4][6];
    float WH[4][5], BS[4];
#pragma unroll
    for (int gi = 0; gi < 4; gi++) {
        const int rr = rows[gi]; const float sc = scl[gi];
#pragma unroll
        for (int p = 0; p < 6; p++) {
            const int i0 = (p < 3) ? 2 * p : 2 * p - 1;   // 0,2,4,5,7,9
            const bool pad = (p == 2) || (p == 5);
            const float w0 = wih[rr * 10 + i0] * sc;
            const float w1 = pad ? 0.f : wih[rr * 10 + i0 + 1] * sc;
            WX[gi][p] = (v2h){(_Float16)w0, (_Float16)w1};
        }
#pragma unroll
        for (int k = 0; k < 5; k++) WH[gi][k] = whh[rr * 5 + k] * sc;
        BS[gi] = (bih[rr] + bhh[rr]) * sc;
    }

    float h[5] = {0.f, 0.f, 0.f, 0.f, 0.f};
    float cp = 0.f, hu_last = 0.f;

    // block-group read pointers: both planes walked by the row's own s.
    const u32* wsd = (const u32*)ws;
    const int g0 = dir ? (GRP - 1) : 0;
    const u32* rp0 = wsd + ((size_t)g0 * B_ + b) * 12;
    const u32* rp1 = wsd + PLANE_DW + ((size_t)g0 * B_ + b) * 12;
    const ptrdiff_t gst = dir ? -(ptrdiff_t)B_ * 12 : (ptrdiff_t)B_ * 12;

    float* op = outbase + ((size_t)(dir ? 255 : 256) * B_ + b) * 10;
    const ptrdiff_t ost = dir ? -(ptrdiff_t)10 * B_ : (ptrdiff_t)10 * B_;

    unsigned short* gw = gtemp + (size_t)bid * 64 + l64;

    struct A4 { float a0, a1, a2, a3; };

    auto dots = [&](const v2h (&xin)[6]) -> A4 {
        A4 v;
        v.a0 = BS[0]; v.a1 = BS[1]; v.a2 = BS[2]; v.a3 = BS[3];
#pragma unroll
        for (int p = 0; p < 6; p++) {
            v.a0 = dot2h(xin[p], WX[0][p], v.a0);
            v.a1 = dot2h(xin[p], WX[1][p], v.a1);
            v.a2 = dot2h(xin[p], WX[2][p], v.a2);
            v.a3 = dot2h(xin[p], WX[3][p], v.a3);
        }
        return v;
    };

    auto cell = [&](A4 v) -> float {
#pragma unroll
        for (int k = 0; k < 5; k++) {
            v.a0 = fmaf(WH[0][k], h[k], v.a0);
            v.a1 = fmaf(WH[1][k], h[k], v.a1);
            v.a2 = fmaf(WH[2][k], h[k], v.a2);
            v.a3 = fmaf(WH[3][k], h[k], v.a3);
        }
        const float ig = rcp_(1.0f + exp2_(v.a0));
        const float fg = rcp_(1.0f + exp2_(v.a1));
        const float g2 = fmaf(-2.0f * T2E, rcp_(1.0f + exp2_(v.a2)), T2E);
        const float og = rcp_(1.0f + exp2_(v.a3));
        cp = fmaf(fg, cp, ig * g2);
        const float th = fmaf(-2.0f, rcp_(1.0f + exp2_(cp)), 1.0f);
        const float hu = og * th;
        hu_last = hu;
        return hu;
    };

    auto bcast = [&](float hu) {
#pragma unroll
        for (int k = 0; k < 5; k++) h[k] = bperm(bidx[k], hu);
    };

    u32 A0[12], A1[12], B0[12], B1[12];
    v2h xt[6];

    auto ldg = [&](u32 (&P0)[12], u32 (&P1)[12]) {
        __builtin_memcpy(P0, __builtin_assume_aligned(rp0, 16), 48);
        __builtin_memcpy(P1, __builtin_assume_aligned(rp1, 16), 48);
        rp0 += gst; rp1 += gst;
        sbar();
    };

    // slot select (p compile-time after unroll): plane0 slot = dir?3-p:p,
    // plane1 slot = dir?p:3-p  (verified: fwd t=5 -> P0 slot1/P1 slot2;
    // bwd t=5 (s=506) -> P0 slot2/P1 slot1).
    auto mkx = [&](const u32 (&P0)[12], const u32 (&P1)[12], int p) {
#pragma unroll
        for (int j = 0; j < 3; j++) {
            const u32 a = dir ? P0[j * 4 + 3 - p] : P0[j * 4 + p];
            const u32 c = dir ? P1[j * 4 + p]     : P1[j * 4 + 3 - p];
            __builtin_memcpy(&xt[j], &a, 4);
            __builtin_memcpy(&xt[3 + j], &c, 4);
        }
    };

    // phase steps (x pre-assembled in xt)
    auto s1L = [&](int t) {
        A4 a = dots(xt);
        const float hu = cell(a); bcast(hu);
        if (lw) lt[t * 60 + l64] = f2h(hu);
    };
    auto s1G = [&]() {
        A4 a = dots(xt);
        const float hu = cell(a); bcast(hu);
        *gw = f2h(hu); gw += GSTR;
    };
    auto s2G = [&](unsigned short pvs) {
        A4 a = dots(xt);
        const float pv = h2f(pvs);
        const float hu = cell(a); bcast(hu);
        if (st) { op[dir5 + uc] = hu; op[5 - dir5 + uc] = pv; }
        op += ost;
    };
    auto s2L = [&](int t) {
        const float pv = h2f(lt[(511 - t) * 60 + ps]);
        A4 a = dots(xt);
        const float hu = cell(a); bcast(hu);
        if (st) { op[dir5 + uc] = hu; op[5 - dir5 + uc] = pv; }
        op += ost;
    };

    ldg(A0, A1);    // own group 0 (t=0..3)
    ldg(B0, B1);    // own group 1 (t=4..7)

    // phi1a: t = 0..207 (LDS stash)
#pragma unroll 1
    for (int t = 0; t < TL; t += 8) {
        mkx(A0, A1, 0); s1L(t + 0);
        mkx(A0, A1, 1); s1L(t + 1);
        mkx(A0, A1, 2); s1L(t + 2);
        mkx(A0, A1, 3); s1L(t + 3);
        ldg(A0, A1);
        mkx(B0, B1, 0); s1L(t + 4);
        mkx(B0, B1, 1); s1L(t + 5);
        mkx(B0, B1, 2); s1L(t + 6);
        mkx(B0, B1, 3); s1L(t + 7);
        ldg(B0, B1);
    }
    // phi1b: t = 208..255 (global stash rows 0..47)
#pragma unroll 1
    for (int t = TL; t < 256; t += 8) {
        mkx(A0, A1, 0); s1G();
        mkx(A0, A1, 1); s1G();
        mkx(A0, A1, 2); s1G();
        mkx(A0, A1, 3); s1G();
        ldg(A0, A1);
        mkx(B0, B1, 0); s1G();
        mkx(B0, B1, 1); s1G();
        mkx(B0, B1, 2); s1G();
        mkx(B0, B1, 3); s1G();
        ldg(B0, B1);
    }
    // drain: spill row 47 (written t=255) is read at t=256 by this wave.
    asm volatile("s_waitcnt vmcnt(0)" ::: "memory");
    // partner ring, depth 4: at step t (256..303) partner = spill row 303-t.
    const unsigned short* gb = gtemp + (size_t)bid * 64 + ps;
    unsigned short q0 = gb[(size_t)47 * GSTR];
    unsigned short q1 = gb[(size_t)46 * GSTR];
    unsigned short q2 = gb[(size_t)45 * GSTR];
    unsigned short q3 = gb[(size_t)44 * GSTR];
    const unsigned short* grq = gb + (size_t)43 * GSTR;
    // phi2a: t = 256..303 (partner from spill ring); last 4 ring reloads
    // hit the guard rows below gtemp (unused).
#pragma unroll 1
    for (int t = 256; t < 304; t += 8) {
        mkx(A0, A1, 0); s2G(q0); q0 = *grq; grq -= GSTR;
        mkx(A0, A1, 1); s2G(q1); q1 = *grq; grq -= GSTR;
        mkx(A0, A1, 2); s2G(q2); q2 = *grq; grq -= GSTR;
        mkx(A0, A1, 3); s2G(q3); q3 = *grq; grq -= GSTR;
        ldg(A0, A1);
        mkx(B0, B1, 0); s2G(q0); q0 = *grq; grq -= GSTR;
        mkx(B0, B1, 1); s2G(q1); q1 = *grq; grq -= GSTR;
        mkx(B0, B1, 2); s2G(q2); q2 = *grq; grq -= GSTR;
        mkx(B0, B1, 3); s2G(q3); q3 = *grq; grq -= GSTR;
        ldg(B0, B1);
    }
    // phi2b: t = 304..503 (partner from LDS row 511-t)
#pragma unroll 1
    for (int t = 304; t < 504; t += 8) {
        mkx(A0, A1, 0); s2L(t + 0);
        mkx(A0, A1, 1); s2L(t + 1);
        mkx(A0, A1, 2); s2L(t + 2);
        mkx(A0, A1, 3); s2L(t + 3);
        ldg(A0, A1);
        mkx(B0, B1, 0); s2L(t + 4);
        mkx(B0, B1, 1); s2L(t + 5);
        mkx(B0, B1, 2); s2L(t + 6);
        mkx(B0, B1, 3); s2L(t + 7);
        ldg(B0, B1);
    }
    // tail: t = 504..511 (groups 126,127 already resident; no loads)
    mkx(A0, A1, 0); s2L(504);
    mkx(A0, A1, 1); s2L(505);
    mkx(A0, A1, 2); s2L(506);
    mkx(A0, A1, 3); s2L(507);
    mkx(B0, B1, 0); s2L(508);
    mkx(B0, B1, 1); s2L(509);
    mkx(B0, B1, 2); s2L(510);
    mkx(B0, B1, 3); s2L(511);

    const size_t OUTE = (size_t)S_ * B_ * 10;
    float* hn = outbase + OUTE + ((size_t)(2 + dir) * B_ + b) * 5;
    float* cn = hn + (size_t)4 * B_ * 5;
    if (st) { hn[uc] = hu_last; cn[uc] = cp * IT2E; }
}

extern "C" void kernel_launch(void* const* d_in, const int* in_sizes, int n_in,
                              void* d_out, int out_size, void* d_ws, size_t ws_size,
                              hipStream_t stream) {
    const float* x       = (const float*)d_in[0];
    const float* wih_l0  = (const float*)d_in[1];
    const float* whh_l0  = (const float*)d_in[2];
    const float* bih_l0  = (const float*)d_in[3];
    const float* bhh_l0  = (const float*)d_in[4];
    const float* wih_l0r = (const float*)d_in[5];
    const float* whh_l0r = (const float*)d_in[6];
    const float* bih_l0r = (const float*)d_in[7];
    const float* bhh_l0r = (const float*)d_in[8];
    const float* wih_l1  = (const float*)d_in[9];
    const float* whh_l1  = (const float*)d_in[10];
    const float* bih_l1  = (const float*)d_in[11];
    const float* bhh_l1  = (const float*)d_in[12];
    const float* wih_l1r = (const float*)d_in[13];
    const float* whh_l1r = (const float*)d_in[14];
    const float* bih_l1r = (const float*)d_in[15];
    const float* bhh_l1r = (const float*)d_in[16];

    float* out = (float*)d_out;
    unsigned short* ws = (unsigned short*)d_ws;   // 2 planes * 50.3 MB (blocked)
    // spill: 4 guard rows + 48 data rows, each 1366*64 shorts (~9.1 MB total)
    unsigned short* gtemp = ws + (size_t)2 * S_ * B_ * 6 + (size_t)4 * GSTR;

    // layer0: 16384 (dir,row) sequences, 12 per wave -> 1366 single-wave blocks
    dim3 grid0(1366), block(64);
    lstm_layer0<<<grid0, block, 0, stream>>>(x,
        wih_l0, whh_l0, bih_l0, bhh_l0,
        wih_l0r, whh_l0r, bih_l0r, bhh_l0r,
        ws, out);
    // layer1: 6 b-values x 2 dirs per wave -> 1366 blocks (12 rows/wave)
    dim3 grid1(GD1);
    lstm_layer1<<<grid1, block, 0, stream>>>(ws,
        wih_l1, whh_l1, bih_l1, bhh_l1,
        wih_l1r, whh_l1r, bih_l1r, bhh_l1r,
        out, gtemp);
}